// Round 1
// baseline (2175.481 us; speedup 1.0000x reference)
//
#include <hip/hip_runtime.h>
#include <math.h>

#define NPTS 524288
#define EDIM 16
#define RES  128
#define HDIM 128
#define DIN  19   // EDIM + 3

// ---------------------------------------------------------------------------
// Transpose W1 [HDIM x HDIM] row-major -> W1T (W1T[k*H + j] = W1[j*H + k])
// ---------------------------------------------------------------------------
__global__ void transpose_w1(const float* __restrict__ W1, float* __restrict__ W1T) {
    int idx = blockIdx.x * 256 + threadIdx.x;
    if (idx < HDIM * HDIM) {
        int j = idx >> 7;
        int k = idx & 127;
        W1T[k * HDIM + j] = W1[j * HDIM + k];
    }
}

// Load 16 consecutive floats (64B-aligned corner) as 4x float4
#define LOAD16(g)                                   \
    float4 q0 = *(const float4*)((g) + 0);          \
    float4 q1 = *(const float4*)((g) + 4);          \
    float4 q2 = *(const float4*)((g) + 8);          \
    float4 q3 = *(const float4*)((g) + 12);

// ---------------------------------------------------------------------------
// Fused: trilinear embed -> SIREN fwd -> sdf, + full VJP w.r.t. p.
// One thread per point. Weights read with wave-uniform indices (scalar loads).
// RS/CS: row/col stride of the W1-matrix argument (W1T: RS=HDIM,CS=1).
// ---------------------------------------------------------------------------
template<int RS, int CS>
__global__ __launch_bounds__(256, 2)
void sdf_fused(const float* __restrict__ pos,
               const float* __restrict__ gridp,
               const float* __restrict__ W0,
               const float* __restrict__ b0,
               const float* __restrict__ W1m,
               const float* __restrict__ b1,
               const float* __restrict__ Wo,
               const float* __restrict__ bo,
               float* __restrict__ out) {
    const int i = blockIdx.x * 256 + threadIdx.x;
    if (i >= NPTS) return;
    const float W0S = 30.0f;

    // p = positions*0.5 + 0.5
    const float px = fmaf(pos[3 * i + 0], 0.5f, 0.5f);
    const float py = fmaf(pos[3 * i + 1], 0.5f, 0.5f);
    const float pz = fmaf(pos[3 * i + 2], 0.5f, 0.5f);

    // trilinear setup (matches reference: i0 = clip(floor(x),0,R-2); f = x - i0)
    const float x0 = px * 127.0f, x1 = py * 127.0f, x2 = pz * 127.0f;
    int i0 = (int)floorf(x0); i0 = i0 < 0 ? 0 : (i0 > 126 ? 126 : i0);
    int i1 = (int)floorf(x1); i1 = i1 < 0 ? 0 : (i1 > 126 ? 126 : i1);
    int i2 = (int)floorf(x2); i2 = i2 < 0 ? 0 : (i2 > 126 ? 126 : i2);
    const float f0 = x0 - (float)i0;
    const float f1 = x1 - (float)i1;
    const float f2 = x2 - (float)i2;

    const float wx1 = f0, wx0 = 1.0f - f0;
    const float wy1 = f1, wy0 = 1.0f - f1;
    const float wz1 = f2, wz0 = 1.0f - f2;

    const int OX = RES * RES * EDIM;   // 262144
    const int OY = RES * EDIM;         // 2048
    const int OZ = EDIM;               // 16
    const float* gb = gridp + ((size_t)((i0 * RES + i1) * RES + i2)) * EDIM;

    // corner weights, index c = dx*4 + dy*2 + dz  (static unroll only)
    float cw[8];
    cw[0] = wx0 * wy0 * wz0;  cw[1] = wx0 * wy0 * wz1;
    cw[2] = wx0 * wy1 * wz0;  cw[3] = wx0 * wy1 * wz1;
    cw[4] = wx1 * wy0 * wz0;  cw[5] = wx1 * wy0 * wz1;
    cw[6] = wx1 * wy1 * wz0;  cw[7] = wx1 * wy1 * wz1;

    // ---- gather + embed ----
    float v[DIN];
#pragma unroll
    for (int e = 0; e < EDIM; ++e) v[e] = 0.0f;

#pragma unroll
    for (int c = 0; c < 8; ++c) {
        const float* g = gb + ((c >> 2) & 1) * OX + ((c >> 1) & 1) * OY + (c & 1) * OZ;
        LOAD16(g);
        const float wc = cw[c];
        v[0]  = fmaf(wc, q0.x, v[0]);   v[1]  = fmaf(wc, q0.y, v[1]);
        v[2]  = fmaf(wc, q0.z, v[2]);   v[3]  = fmaf(wc, q0.w, v[3]);
        v[4]  = fmaf(wc, q1.x, v[4]);   v[5]  = fmaf(wc, q1.y, v[5]);
        v[6]  = fmaf(wc, q1.z, v[6]);   v[7]  = fmaf(wc, q1.w, v[7]);
        v[8]  = fmaf(wc, q2.x, v[8]);   v[9]  = fmaf(wc, q2.y, v[9]);
        v[10] = fmaf(wc, q2.z, v[10]);  v[11] = fmaf(wc, q2.w, v[11]);
        v[12] = fmaf(wc, q3.x, v[12]);  v[13] = fmaf(wc, q3.y, v[13]);
        v[14] = fmaf(wc, q3.z, v[14]);  v[15] = fmaf(wc, q3.w, v[15]);
    }
    v[16] = px; v[17] = py; v[18] = pz;

    // ---- fused layer0 + layer2-forward (outer-k; h1 never materialized) ----
    float a1[HDIM];
#pragma unroll
    for (int j = 0; j < HDIM; ++j) a1[j] = 0.0f;

    for (int k = 0; k < HDIM; ++k) {
        float a0 = b0[k];
        const float* w0r = W0 + k * DIN;
#pragma unroll
        for (int m = 0; m < DIN; ++m) a0 = fmaf(w0r[m], v[m], a0);
        const float h1 = __sinf(W0S * a0);
        const float* wr = W1m + k * RS;
#pragma unroll
        for (int j = 0; j < HDIM; ++j) a1[j] = fmaf(wr[j * CS], h1, a1[j]);
    }

    // ---- layer2 finish: sdf, and overwrite a1[j] <- da1[j] ----
    float sdf = bo[0];
#pragma unroll
    for (int j = 0; j < HDIM; ++j) {
        const float t  = W0S * (a1[j] + b1[j]);
        const float s  = __sinf(t);
        const float c  = __cosf(t);
        const float wo = Wo[j];
        sdf   = fmaf(wo, s, sdf);
        a1[j] = (W0S * wo) * c;          // da1_j
    }

    // ---- backward: dv = W0^T (30*cos(30*a0) .* (W1^T da1)) ----
    float dv[DIN];
#pragma unroll
    for (int m = 0; m < DIN; ++m) dv[m] = 0.0f;

    for (int k = 0; k < HDIM; ++k) {
        const float* wr = W1m + k * RS;
        float s0 = 0.0f, s1 = 0.0f, s2 = 0.0f, s3 = 0.0f;
#pragma unroll
        for (int j = 0; j < HDIM; j += 4) {
            s0 = fmaf(wr[(j + 0) * CS], a1[j + 0], s0);
            s1 = fmaf(wr[(j + 1) * CS], a1[j + 1], s1);
            s2 = fmaf(wr[(j + 2) * CS], a1[j + 2], s2);
            s3 = fmaf(wr[(j + 3) * CS], a1[j + 3], s3);
        }
        const float dh1 = (s0 + s1) + (s2 + s3);

        float a0 = b0[k];
        const float* w0r = W0 + k * DIN;
#pragma unroll
        for (int m = 0; m < DIN; ++m) a0 = fmaf(w0r[m], v[m], a0);
        const float da0 = dh1 * W0S * __cosf(W0S * a0);
#pragma unroll
        for (int m = 0; m < DIN; ++m) dv[m] = fmaf(w0r[m], da0, dv[m]);
    }

    // ---- gradient combine: second gather, dot corners with dv[0:16] ----
    float sc[8];
#pragma unroll
    for (int c = 0; c < 8; ++c) {
        const float* g = gb + ((c >> 2) & 1) * OX + ((c >> 1) & 1) * OY + (c & 1) * OZ;
        LOAD16(g);
        float t0 = q0.x * dv[0]  + q0.y * dv[1]  + q0.z * dv[2]  + q0.w * dv[3];
        float t1 = q1.x * dv[4]  + q1.y * dv[5]  + q1.z * dv[6]  + q1.w * dv[7];
        float t2 = q2.x * dv[8]  + q2.y * dv[9]  + q2.z * dv[10] + q2.w * dv[11];
        float t3 = q3.x * dv[12] + q3.y * dv[13] + q3.z * dv[14] + q3.w * dv[15];
        sc[c] = (t0 + t1) + (t2 + t3);
    }

    const float gx = 127.0f * (wy0 * wz0 * (sc[4] - sc[0]) + wy0 * wz1 * (sc[5] - sc[1]) +
                               wy1 * wz0 * (sc[6] - sc[2]) + wy1 * wz1 * (sc[7] - sc[3]));
    const float gy = 127.0f * (wx0 * wz0 * (sc[2] - sc[0]) + wx0 * wz1 * (sc[3] - sc[1]) +
                               wx1 * wz0 * (sc[6] - sc[4]) + wx1 * wz1 * (sc[7] - sc[5]));
    const float gz = 127.0f * (wx0 * wy0 * (sc[1] - sc[0]) + wx0 * wy1 * (sc[3] - sc[2]) +
                               wx1 * wy0 * (sc[5] - sc[4]) + wx1 * wy1 * (sc[7] - sc[6]));

    out[i] = sdf;
    out[NPTS + 3 * i + 0] = gx + dv[16];
    out[NPTS + 3 * i + 1] = gy + dv[17];
    out[NPTS + 3 * i + 2] = gz + dv[18];
}

// ---------------------------------------------------------------------------
extern "C" void kernel_launch(void* const* d_in, const int* in_sizes, int n_in,
                              void* d_out, int out_size, void* d_ws, size_t ws_size,
                              hipStream_t stream) {
    const float* pos  = (const float*)d_in[0];
    const float* grid = (const float*)d_in[1];
    const float* W0   = (const float*)d_in[2];
    const float* b0   = (const float*)d_in[3];
    const float* W1   = (const float*)d_in[4];
    const float* b1   = (const float*)d_in[5];
    const float* Wo   = (const float*)d_in[6];
    const float* bo   = (const float*)d_in[7];
    float* out = (float*)d_out;

    const int nblk = NPTS / 256;
    if (ws_size >= (size_t)(HDIM * HDIM * sizeof(float))) {
        float* W1T = (float*)d_ws;
        transpose_w1<<<(HDIM * HDIM + 255) / 256, 256, 0, stream>>>(W1, W1T);
        sdf_fused<HDIM, 1><<<nblk, 256, 0, stream>>>(pos, grid, W0, b0, W1T, b1, Wo, bo, out);
    } else {
        // fallback: read W1 with transposed indexing (strided scalar loads)
        sdf_fused<1, HDIM><<<nblk, 256, 0, stream>>>(pos, grid, W0, b0, W1, b1, Wo, bo, out);
    }
}

// Round 2
// 1025.578 us; speedup vs baseline: 2.1212x; 2.1212x over previous
//
#include <hip/hip_runtime.h>
#include <math.h>

#define NPTS 524288
#define EDIM 16
#define RES  128
#define HDIM 128
#define DIN  19   // EDIM + 3
#define JCHUNK 64

// ---------------------------------------------------------------------------
// Transpose W1 [HDIM x HDIM] row-major -> W1T (W1T[k*H + j] = W1[j*H + k])
// ---------------------------------------------------------------------------
__global__ void transpose_w1(const float* __restrict__ W1, float* __restrict__ W1T) {
    int idx = blockIdx.x * 256 + threadIdx.x;
    if (idx < HDIM * HDIM) {
        int j = idx >> 7;
        int k = idx & 127;
        W1T[k * HDIM + j] = W1[j * HDIM + k];
    }
}

// Load 16 consecutive floats (64B-aligned corner) as 4x float4
#define LOAD16(g)                                   \
    float4 q0 = *(const float4*)((g) + 0);          \
    float4 q1 = *(const float4*)((g) + 4);          \
    float4 q2 = *(const float4*)((g) + 8);          \
    float4 q3 = *(const float4*)((g) + 12);

// ---------------------------------------------------------------------------
// Fused trilinear + SIREN fwd + VJP. One thread per point.
// j-dimension processed in 2 chunks of 64; each chunk does fwd accum ->
// da1 -> bwd before the next, so only 64 accumulator regs are live.
// Weights read with wave-uniform indices (scalar loads).
// ---------------------------------------------------------------------------
template<int RS, int CS>
__global__ __launch_bounds__(256, 2)
void sdf_fused(const float* __restrict__ pos,
               const float* __restrict__ gridp,
               const float* __restrict__ W0,
               const float* __restrict__ b0,
               const float* __restrict__ W1m,
               const float* __restrict__ b1,
               const float* __restrict__ Wo,
               const float* __restrict__ bo,
               float* __restrict__ out) {
    const int i = blockIdx.x * 256 + threadIdx.x;
    if (i >= NPTS) return;
    const float W0S = 30.0f;

    // p = positions*0.5 + 0.5
    const float px = fmaf(pos[3 * i + 0], 0.5f, 0.5f);
    const float py = fmaf(pos[3 * i + 1], 0.5f, 0.5f);
    const float pz = fmaf(pos[3 * i + 2], 0.5f, 0.5f);

    // trilinear setup
    const float x0 = px * 127.0f, x1 = py * 127.0f, x2 = pz * 127.0f;
    int i0 = (int)floorf(x0); i0 = i0 < 0 ? 0 : (i0 > 126 ? 126 : i0);
    int i1 = (int)floorf(x1); i1 = i1 < 0 ? 0 : (i1 > 126 ? 126 : i1);
    int i2 = (int)floorf(x2); i2 = i2 < 0 ? 0 : (i2 > 126 ? 126 : i2);
    const float f0 = x0 - (float)i0;
    const float f1 = x1 - (float)i1;
    const float f2 = x2 - (float)i2;

    const float wx1 = f0, wx0 = 1.0f - f0;
    const float wy1 = f1, wy0 = 1.0f - f1;
    const float wz1 = f2, wz0 = 1.0f - f2;

    const int OX = RES * RES * EDIM;
    const int OY = RES * EDIM;
    const int OZ = EDIM;
    const float* gb = gridp + ((size_t)((i0 * RES + i1) * RES + i2)) * EDIM;

    float cw[8];
    cw[0] = wx0 * wy0 * wz0;  cw[1] = wx0 * wy0 * wz1;
    cw[2] = wx0 * wy1 * wz0;  cw[3] = wx0 * wy1 * wz1;
    cw[4] = wx1 * wy0 * wz0;  cw[5] = wx1 * wy0 * wz1;
    cw[6] = wx1 * wy1 * wz0;  cw[7] = wx1 * wy1 * wz1;

    // ---- gather + embed ----
    float v[DIN];
#pragma unroll
    for (int e = 0; e < EDIM; ++e) v[e] = 0.0f;

#pragma unroll
    for (int c = 0; c < 8; ++c) {
        const float* g = gb + ((c >> 2) & 1) * OX + ((c >> 1) & 1) * OY + (c & 1) * OZ;
        LOAD16(g);
        const float wc = cw[c];
        v[0]  = fmaf(wc, q0.x, v[0]);   v[1]  = fmaf(wc, q0.y, v[1]);
        v[2]  = fmaf(wc, q0.z, v[2]);   v[3]  = fmaf(wc, q0.w, v[3]);
        v[4]  = fmaf(wc, q1.x, v[4]);   v[5]  = fmaf(wc, q1.y, v[5]);
        v[6]  = fmaf(wc, q1.z, v[6]);   v[7]  = fmaf(wc, q1.w, v[7]);
        v[8]  = fmaf(wc, q2.x, v[8]);   v[9]  = fmaf(wc, q2.y, v[9]);
        v[10] = fmaf(wc, q2.z, v[10]);  v[11] = fmaf(wc, q2.w, v[11]);
        v[12] = fmaf(wc, q3.x, v[12]);  v[13] = fmaf(wc, q3.y, v[13]);
        v[14] = fmaf(wc, q3.z, v[14]);  v[15] = fmaf(wc, q3.w, v[15]);
    }
    v[16] = px; v[17] = py; v[18] = pz;

    float dv[DIN];
#pragma unroll
    for (int m = 0; m < DIN; ++m) dv[m] = 0.0f;
    float sdf = bo[0];

    // ---- process j in chunks of JCHUNK: fwd -> da1 -> bwd per chunk ----
#pragma unroll 1
    for (int cch = 0; cch < HDIM / JCHUNK; ++cch) {
        const int j0 = cch * JCHUNK;

        float a1c[JCHUNK];
#pragma unroll
        for (int jj = 0; jj < JCHUNK; ++jj) a1c[jj] = 0.0f;

        // forward: a1c[jj] += W1T[k][j0+jj] * sin(30*a0_k)
#pragma unroll 1
        for (int k = 0; k < HDIM; ++k) {
            float a0 = b0[k];
            const float* w0r = W0 + k * DIN;
#pragma unroll
            for (int m = 0; m < DIN; ++m) a0 = fmaf(w0r[m], v[m], a0);
            const float h1 = __sinf(W0S * a0);
            const float* wr = W1m + k * RS + j0 * CS;
#pragma unroll
            for (int jj = 0; jj < JCHUNK; ++jj)
                a1c[jj] = fmaf(wr[jj * CS], h1, a1c[jj]);
        }

        // mid: sdf contribution + overwrite a1c <- da1
#pragma unroll
        for (int jj = 0; jj < JCHUNK; ++jj) {
            const float t = W0S * (a1c[jj] + b1[j0 + jj]);
            float s, co;
            __sincosf(t, &s, &co);
            const float wo = Wo[j0 + jj];
            sdf = fmaf(wo, s, sdf);
            a1c[jj] = (W0S * wo) * co;
        }

        // backward: dv[m] += W0[k][m] * 30*cos(30*a0_k) * sum_jj W1T[k][j0+jj]*da1[jj]
#pragma unroll 1
        for (int k = 0; k < HDIM; ++k) {
            const float* wr = W1m + k * RS + j0 * CS;
            float s0 = 0.0f, s1 = 0.0f, s2 = 0.0f, s3 = 0.0f;
#pragma unroll
            for (int jj = 0; jj < JCHUNK; jj += 4) {
                s0 = fmaf(wr[(jj + 0) * CS], a1c[jj + 0], s0);
                s1 = fmaf(wr[(jj + 1) * CS], a1c[jj + 1], s1);
                s2 = fmaf(wr[(jj + 2) * CS], a1c[jj + 2], s2);
                s3 = fmaf(wr[(jj + 3) * CS], a1c[jj + 3], s3);
            }
            const float dh1 = (s0 + s1) + (s2 + s3);

            float a0 = b0[k];
            const float* w0r = W0 + k * DIN;
#pragma unroll
            for (int m = 0; m < DIN; ++m) a0 = fmaf(w0r[m], v[m], a0);
            const float da0 = dh1 * W0S * __cosf(W0S * a0);
#pragma unroll
            for (int m = 0; m < DIN; ++m) dv[m] = fmaf(w0r[m], da0, dv[m]);
        }
    }

    // ---- gradient combine: second gather, dot corners with dv[0:16] ----
    float sc[8];
#pragma unroll
    for (int c = 0; c < 8; ++c) {
        const float* g = gb + ((c >> 2) & 1) * OX + ((c >> 1) & 1) * OY + (c & 1) * OZ;
        LOAD16(g);
        float t0 = q0.x * dv[0]  + q0.y * dv[1]  + q0.z * dv[2]  + q0.w * dv[3];
        float t1 = q1.x * dv[4]  + q1.y * dv[5]  + q1.z * dv[6]  + q1.w * dv[7];
        float t2 = q2.x * dv[8]  + q2.y * dv[9]  + q2.z * dv[10] + q2.w * dv[11];
        float t3 = q3.x * dv[12] + q3.y * dv[13] + q3.z * dv[14] + q3.w * dv[15];
        sc[c] = (t0 + t1) + (t2 + t3);
    }

    const float gx = 127.0f * (wy0 * wz0 * (sc[4] - sc[0]) + wy0 * wz1 * (sc[5] - sc[1]) +
                               wy1 * wz0 * (sc[6] - sc[2]) + wy1 * wz1 * (sc[7] - sc[3]));
    const float gy = 127.0f * (wx0 * wz0 * (sc[2] - sc[0]) + wx0 * wz1 * (sc[3] - sc[1]) +
                               wx1 * wz0 * (sc[6] - sc[4]) + wx1 * wz1 * (sc[7] - sc[5]));
    const float gz = 127.0f * (wx0 * wy0 * (sc[1] - sc[0]) + wx0 * wy1 * (sc[3] - sc[2]) +
                               wx1 * wy0 * (sc[5] - sc[4]) + wx1 * wy1 * (sc[7] - sc[6]));

    out[i] = sdf;
    out[NPTS + 3 * i + 0] = gx + dv[16];
    out[NPTS + 3 * i + 1] = gy + dv[17];
    out[NPTS + 3 * i + 2] = gz + dv[18];
}

// ---------------------------------------------------------------------------
extern "C" void kernel_launch(void* const* d_in, const int* in_sizes, int n_in,
                              void* d_out, int out_size, void* d_ws, size_t ws_size,
                              hipStream_t stream) {
    const float* pos  = (const float*)d_in[0];
    const float* grid = (const float*)d_in[1];
    const float* W0   = (const float*)d_in[2];
    const float* b0   = (const float*)d_in[3];
    const float* W1   = (const float*)d_in[4];
    const float* b1   = (const float*)d_in[5];
    const float* Wo   = (const float*)d_in[6];
    const float* bo   = (const float*)d_in[7];
    float* out = (float*)d_out;

    const int nblk = NPTS / 256;
    if (ws_size >= (size_t)(HDIM * HDIM * sizeof(float))) {
        float* W1T = (float*)d_ws;
        transpose_w1<<<(HDIM * HDIM + 255) / 256, 256, 0, stream>>>(W1, W1T);
        sdf_fused<HDIM, 1><<<nblk, 256, 0, stream>>>(pos, grid, W0, b0, W1T, b1, Wo, bo, out);
    } else {
        sdf_fused<1, HDIM><<<nblk, 256, 0, stream>>>(pos, grid, W0, b0, W1, b1, Wo, bo, out);
    }
}